// Round 1
// baseline (642.240 us; speedup 1.0000x reference)
//
#include <hip/hip_runtime.h>
#include <cmath>

// Problem: N=50000 nodes, E=800000 edges, B=1, F=D=64, H=4, d=16, M=8.
// Wave (64 lanes) == one node's (h,dd) layout: lane l -> h=l>>4, dd=l&15.

__device__ __forceinline__ float softplus_f(float z){
  // log1p(exp(z)) stable
  return fmaxf(z, 0.f) + log1pf(__expf(-fabsf(z)));
}

// ---------------- K1: projections Q,K,T,V + WeQ[h] = sum_dd We[h,dd]*Q[n,h,dd]
__global__ __launch_bounds__(256) void k_proj(
    const float* __restrict__ x_src, const float* __restrict__ x_dst,
    const float* __restrict__ Wq, const float* __restrict__ Wk,
    const float* __restrict__ Wt, const float* __restrict__ Wv,
    const float* __restrict__ We,
    float* __restrict__ Qo, float* __restrict__ Ko,
    float* __restrict__ To, float* __restrict__ Vo,
    float* __restrict__ WeQ, int N)
{
  int l   = threadIdx.x & 63;
  int mat = threadIdx.x >> 6;          // wave-uniform
  int n   = blockIdx.x * 64 + l;
  if (n >= N) return;
  const float* x = ((mat==0) ? x_dst : x_src) + (size_t)n*64;
  const float* W = (mat==0) ? Wq : (mat==1) ? Wk : (mat==2) ? Wt : Wv;
  float*       O = (mat==0) ? Qo : (mat==1) ? Ko : (mat==2) ? To : Vo;

  float xr[64];
  const float4* x4 = (const float4*)x;
  #pragma unroll
  for (int i=0;i<16;i++){ float4 v=x4[i]; xr[4*i]=v.x; xr[4*i+1]=v.y; xr[4*i+2]=v.z; xr[4*i+3]=v.w; }

  float4* O4 = (float4*)(O + (size_t)n*64);
  float weq0=0.f, weq1=0.f, weq2=0.f, weq3=0.f;
  #pragma unroll
  for (int jq=0;jq<16;jq++){
    float a0=0.f,a1=0.f,a2=0.f,a3=0.f;
    const float* Wr = W + jq*256;      // rows jq*4 .. jq*4+3, wave-uniform -> s_load
    #pragma unroll
    for (int f=0;f<64;f++){
      float xf = xr[f];
      a0 = fmaf(Wr[      f], xf, a0);
      a1 = fmaf(Wr[ 64 + f], xf, a1);
      a2 = fmaf(Wr[128 + f], xf, a2);
      a3 = fmaf(Wr[192 + f], xf, a3);
    }
    O4[jq] = make_float4(a0,a1,a2,a3);
    if (mat==0){
      float ws = We[jq*4]*a0 + We[jq*4+1]*a1 + We[jq*4+2]*a2 + We[jq*4+3]*a3;
      if      (jq <  4) weq0 += ws;
      else if (jq <  8) weq1 += ws;
      else if (jq < 12) weq2 += ws;
      else              weq3 += ws;
    }
  }
  if (mat==0) *(float4*)(WeQ + (size_t)n*4) = make_float4(weq0,weq1,weq2,weq3);
}

// ---------------- CSR build
__global__ __launch_bounds__(256) void k_hist(const int* __restrict__ dst, int* __restrict__ deg, int E){
  int i = blockIdx.x*256 + threadIdx.x;
  if (i < E) atomicAdd(&deg[dst[i]], 1);
}

__global__ __launch_bounds__(1024) void k_scan1(const int* __restrict__ deg, int* __restrict__ rowptr,
                                                int* __restrict__ bsum, int N){
  __shared__ int sh[1024];
  int t = threadIdx.x;
  int i = blockIdx.x*1024 + t;
  int v = (i < N) ? deg[i] : 0;
  sh[t] = v; __syncthreads();
  int x = v;
  for (int off=1; off<1024; off<<=1){
    int y = (t >= off) ? sh[t-off] : 0;
    __syncthreads();
    x += y; sh[t] = x;
    __syncthreads();
  }
  if (i < N) rowptr[i] = x - v;            // local exclusive
  if (t == 1023) bsum[blockIdx.x] = x;     // chunk total
}

__global__ __launch_bounds__(64) void k_scan2(int* __restrict__ bsum, int nb){
  int l = threadIdx.x;
  int v0 = (l < nb) ? bsum[l] : 0;
  int v = v0;
  for (int off=1; off<64; off<<=1){
    int y = __shfl_up(v, off);
    if (l >= off) v += y;
  }
  if (l < nb) bsum[l] = v - v0;            // exclusive
}

__global__ __launch_bounds__(1024) void k_scan3(int* __restrict__ rowptr, const int* __restrict__ bsum,
                                                int N, int E){
  int i = blockIdx.x*1024 + threadIdx.x;
  if (i < N) rowptr[i] += bsum[blockIdx.x];
  if (i == 0) rowptr[N] = E;
}

__global__ __launch_bounds__(256) void k_scatter(const int* __restrict__ dst, const int* __restrict__ rowptr,
                                                 int* __restrict__ fill, int* __restrict__ eidx, int E){
  int i = blockIdx.x*256 + threadIdx.x;
  if (i < E){
    int d_ = dst[i];
    int pos = rowptr[d_] + atomicAdd(&fill[d_], 1);
    eidx[pos] = i;
  }
}

// ---------------- K5: per-dst-node: logits + online softmax + g + MLP -> fi
__global__ __launch_bounds__(256) void k_node(
    const float* __restrict__ Qb, const float* __restrict__ Kb, const float* __restrict__ Tb,
    const float* __restrict__ WeQ, const float* __restrict__ ef, const float* __restrict__ t_in,
    const int* __restrict__ rowptr, const int* __restrict__ eidx, const int* __restrict__ src,
    const float* __restrict__ Wi, const float* __restrict__ bi,
    const float* __restrict__ wiw, const float* __restrict__ scale_i,
    float* __restrict__ e_sorted, float* __restrict__ esum, float* __restrict__ emax,
    float* __restrict__ fi_out, int N)
{
  __shared__ float sWi[128*17];
  __shared__ float sbi[128];
  __shared__ float swiw[128];
  __shared__ float sscale[8];
  __shared__ float g_sh[4][4][17];
  int tid = threadIdx.x;
  for (int i=tid; i<128*17; i+=256) sWi[i] = Wi[i];
  if (tid < 128){ sbi[tid] = bi[tid]; swiw[tid] = wiw[tid]; }
  if (tid < 8)  sscale[tid] = __expf(scale_i[tid]);
  __syncthreads();

  int w = tid>>6, l = tid&63;
  int h = l>>4, il = l&15;
  int n = blockIdx.x*4 + w;               // wave-uniform
  bool act = (n < N);

  float m_h = -INFINITY, s_h = 0.f, g_l = 0.f;
  if (act){
    int row0 = rowptr[n];
    int dg   = rowptr[n+1] - row0;
    float q_l   = Qb[(size_t)n*64 + l];
    float weq_h = WeQ[n*4 + h];
    for (int i2=0; i2<dg; i2++){
      int eid = eidx[row0+i2];
      int sn  = src[eid];
      float kv = Kb[(size_t)sn*64 + l];
      float d4 = kv * q_l;                                // per-head dot over 16 lanes
      d4 += __shfl_xor(d4,1); d4 += __shfl_xor(d4,2);
      d4 += __shfl_xor(d4,4); d4 += __shfl_xor(d4,8);
      float ev = (d4 + ef[eid]*weq_h) * 0.25f;            // /sqrt(16)
      float m_new = fmaxf(m_h, ev);
      float corr  = __expf(m_h - m_new);
      float p     = __expf(ev - m_new);
      s_h = s_h*corr + p;
      g_l = g_l*corr + Tb[(size_t)sn*64 + l]*p;
      m_h = m_new;
      if (il == h) e_sorted[(size_t)(row0+i2)*4 + h] = ev;  // raw logit
    }
    if (il == h){ esum[n*4+h] = s_h; emax[n*4+h] = m_h; }
    float invs = (dg > 0) ? 1.f/s_h : 0.f;
    g_l *= invs;
    g_sh[w][h][il] = g_l;
    if (l < 4) g_sh[w][l][16] = t_in[n];
  }
  __syncthreads();
  if (act){
    // u-phase: lane handles k1=l, k2=l+64 for all 4 heads
    float wi1[17], wi2[17];
    #pragma unroll
    for (int j=0;j<17;j++){ wi1[j] = sWi[l*17 + j]; wi2[j] = sWi[(l+64)*17 + j]; }
    float b1 = sbi[l],  b2 = sbi[l+64];
    float wv1 = swiw[l], wv2 = swiw[l+64];
    float z1[4], z2[4];
    #pragma unroll
    for (int h2=0; h2<4; h2++){
      float a1=b1, a2=b2;
      #pragma unroll
      for (int j=0;j<17;j++){
        float inj = g_sh[w][h2][j];
        a1 = fmaf(wi1[j], inj, a1);
        a2 = fmaf(wi2[j], inj, a2);
      }
      float u1 = __fdividef(1.f, 1.f + __expf(-a1));
      float u2 = __fdividef(1.f, 1.f + __expf(-a2));
      float p1 = u1*wv1, p2 = u2*wv2;
      p1 += __shfl_xor(p1,1); p1 += __shfl_xor(p1,2); p1 += __shfl_xor(p1,4); p1 += __shfl_xor(p1,8);
      p2 += __shfl_xor(p2,1); p2 += __shfl_xor(p2,2); p2 += __shfl_xor(p2,4); p2 += __shfl_xor(p2,8);
      z1[h2] = p1; z2[h2] = p2;
    }
    if (il == 0){
      int m1 = h;                          // l>>4
      float sc1 = sscale[m1], sc2 = sscale[m1+4];
      #pragma unroll
      for (int h2=0; h2<4; h2++){
        fi_out[(size_t)n*32 + h2*8 + m1    ] = sc1*softplus_f(z1[h2]/sc1);
        fi_out[(size_t)n*32 + h2*8 + m1 + 4] = sc2*softplus_f(z2[h2]/sc2);
      }
    }
  }
}

// ---------------- K6: out[n] = x_dst[n] + sum_edges V[src]*( (fi[src]·fm[n]) * ea )
__global__ __launch_bounds__(256) void k_out(
    const float* __restrict__ Vb, const float* __restrict__ fi,
    const float* __restrict__ e_sorted, const float* __restrict__ esum, const float* __restrict__ emax,
    const float* __restrict__ m_in, const float* __restrict__ x_dst,
    const int* __restrict__ rowptr, const int* __restrict__ eidx, const int* __restrict__ src,
    float* __restrict__ out, int N)
{
  int tid = threadIdx.x;
  int w = tid>>6, l = tid&63;
  int h = l>>4;
  int n = blockIdx.x*4 + w;
  if (n >= N) return;
  float o = x_dst[(size_t)n*64 + l];
  float fm[8];
  #pragma unroll
  for (int mm=0; mm<8; mm++) fm[mm] = m_in[n*8 + mm];
  float mh = emax[n*4+h];
  float sh = esum[n*4+h];
  float invs = (sh > 0.f) ? 1.f/sh : 0.f;
  int row0 = rowptr[n], dg = rowptr[n+1] - row0;
  for (int i2=0; i2<dg; i2++){
    int eid = eidx[row0+i2];
    int sn  = src[eid];
    float ev = e_sorted[(size_t)(row0+i2)*4 + h];
    float p  = __expf(ev - mh) * invs;     // ea
    float dot = 0.f;
    #pragma unroll
    for (int mm=0; mm<8; mm++) dot = fmaf(fi[(size_t)sn*32 + h*8 + mm], fm[mm], dot);
    o = fmaf(Vb[(size_t)sn*64 + l], dot*p, o);
  }
  out[(size_t)n*64 + l] = o;
}

extern "C" void kernel_launch(void* const* d_in, const int* in_sizes, int n_in,
                              void* d_out, int out_size, void* d_ws, size_t ws_size,
                              hipStream_t stream)
{
  const float* x_src = (const float*)d_in[0];
  const float* x_dst = (const float*)d_in[1];
  const float* t_in  = (const float*)d_in[2];
  const float* m_in  = (const float*)d_in[3];
  const float* ef    = (const float*)d_in[4];
  const float* Wq    = (const float*)d_in[5];
  const float* Wk    = (const float*)d_in[6];
  const float* Wv    = (const float*)d_in[7];
  const float* Wt    = (const float*)d_in[8];
  const float* We    = (const float*)d_in[9];
  const float* Wi    = (const float*)d_in[10];
  const float* bi    = (const float*)d_in[11];
  const float* wiw   = (const float*)d_in[12];
  const float* sci   = (const float*)d_in[13];
  const int*   src   = (const int*)d_in[14];
  const int*   dst   = (const int*)d_in[15];
  int N = in_sizes[0] / 64;
  int E = in_sizes[14];
  float* out = (float*)d_out;

  char* p = (char*)d_ws;
  auto alloc = [&](size_t bytes)->char*{ char* r = p; p += (bytes + 255) & ~(size_t)255; return r; };
  float* Qb   = (float*)alloc((size_t)N*64*4);
  float* Kb   = (float*)alloc((size_t)N*64*4);
  float* Tb   = (float*)alloc((size_t)N*64*4);
  float* Vb   = (float*)alloc((size_t)N*64*4);
  float* WeQ  = (float*)alloc((size_t)N*4*4);
  float* esum = (float*)alloc((size_t)N*4*4);
  float* emx  = (float*)alloc((size_t)N*4*4);
  float* fi   = (float*)alloc((size_t)N*32*4);
  float* es   = (float*)alloc((size_t)E*4*4);
  int*   deg  = (int*)alloc((size_t)N*4);
  int*   fill = (int*)alloc((size_t)N*4);
  int*   rowp = (int*)alloc((size_t)(N+1)*4);
  int*   eidx = (int*)alloc((size_t)E*4);
  int    NB   = (N + 1023) / 1024;
  int*   bsum = (int*)alloc((size_t)NB*4);

  hipMemsetAsync(deg,  0, (size_t)N*4, stream);
  hipMemsetAsync(fill, 0, (size_t)N*4, stream);

  k_proj<<<(N+63)/64, 256, 0, stream>>>(x_src, x_dst, Wq, Wk, Wt, Wv, We, Qb, Kb, Tb, Vb, WeQ, N);
  k_hist<<<(E+255)/256, 256, 0, stream>>>(dst, deg, E);
  k_scan1<<<NB, 1024, 0, stream>>>(deg, rowp, bsum, N);
  k_scan2<<<1, 64, 0, stream>>>(bsum, NB);
  k_scan3<<<NB, 1024, 0, stream>>>(rowp, bsum, N, E);
  k_scatter<<<(E+255)/256, 256, 0, stream>>>(dst, rowp, fill, eidx, E);
  k_node<<<(N+3)/4, 256, 0, stream>>>(Qb, Kb, Tb, WeQ, ef, t_in, rowp, eidx, src,
                                      Wi, bi, wiw, sci, es, esum, emx, fi, N);
  k_out<<<(N+3)/4, 256, 0, stream>>>(Vb, fi, es, esum, emx, m_in, x_dst, rowp, eidx, src, out, N);
}

// Round 5
// 472.201 us; speedup vs baseline: 1.3601x; 1.3601x over previous
//
#include <hip/hip_runtime.h>
#include <cmath>

// N=50000, E=800000, B=1, F=D=64, H=4, d=16, M=8.
// Wave (64 lanes) == one node's (h,dd): lane l -> h=l>>4, dd=l&15.

__device__ __forceinline__ float softplus_f(float z){
  return fmaxf(z, 0.f) + log1pf(__expf(-fabsf(z)));
}

__device__ __forceinline__ float red16(float v){
  v += __shfl_xor(v,1); v += __shfl_xor(v,2);
  v += __shfl_xor(v,4); v += __shfl_xor(v,8);
  return v;
}

// ---------------- K1: projections Q,K,T,V + WeQ[h]
__global__ __launch_bounds__(256) void k_proj(
    const float* __restrict__ x_src, const float* __restrict__ x_dst,
    const float* __restrict__ Wq, const float* __restrict__ Wk,
    const float* __restrict__ Wt, const float* __restrict__ Wv,
    const float* __restrict__ We,
    float* __restrict__ Qo, float* __restrict__ Ko,
    float* __restrict__ To, float* __restrict__ Vo,
    float* __restrict__ WeQ, int N)
{
  int l   = threadIdx.x & 63;
  int mat = threadIdx.x >> 6;
  int n   = blockIdx.x * 64 + l;
  if (n >= N) return;
  const float* x = ((mat==0) ? x_dst : x_src) + (size_t)n*64;
  const float* W = (mat==0) ? Wq : (mat==1) ? Wk : (mat==2) ? Wt : Wv;
  float*       O = (mat==0) ? Qo : (mat==1) ? Ko : (mat==2) ? To : Vo;

  float xr[64];
  const float4* x4 = (const float4*)x;
  #pragma unroll
  for (int i=0;i<16;i++){ float4 v=x4[i]; xr[4*i]=v.x; xr[4*i+1]=v.y; xr[4*i+2]=v.z; xr[4*i+3]=v.w; }

  float4* O4 = (float4*)(O + (size_t)n*64);
  float weq0=0.f, weq1=0.f, weq2=0.f, weq3=0.f;
  #pragma unroll
  for (int jq=0;jq<16;jq++){
    float a0=0.f,a1=0.f,a2=0.f,a3=0.f;
    const float* Wr = W + jq*256;
    #pragma unroll
    for (int f=0;f<64;f++){
      float xf = xr[f];
      a0 = fmaf(Wr[      f], xf, a0);
      a1 = fmaf(Wr[ 64 + f], xf, a1);
      a2 = fmaf(Wr[128 + f], xf, a2);
      a3 = fmaf(Wr[192 + f], xf, a3);
    }
    O4[jq] = make_float4(a0,a1,a2,a3);
    if (mat==0){
      float ws = We[jq*4]*a0 + We[jq*4+1]*a1 + We[jq*4+2]*a2 + We[jq*4+3]*a3;
      if      (jq <  4) weq0 += ws;
      else if (jq <  8) weq1 += ws;
      else if (jq < 12) weq2 += ws;
      else              weq3 += ws;
    }
  }
  if (mat==0) *(float4*)(WeQ + (size_t)n*4) = make_float4(weq0,weq1,weq2,weq3);
}

// ---------------- CSR build
__global__ __launch_bounds__(256) void k_hist(const int* __restrict__ dst, int* __restrict__ deg, int E){
  int i = blockIdx.x*256 + threadIdx.x;
  if (i < E) atomicAdd(&deg[dst[i]], 1);
}

__global__ __launch_bounds__(1024) void k_scan1(const int* __restrict__ deg, int* __restrict__ rowptr,
                                                int* __restrict__ bsum, int N){
  __shared__ int sh[1024];
  int t = threadIdx.x;
  int i = blockIdx.x*1024 + t;
  int v = (i < N) ? deg[i] : 0;
  sh[t] = v; __syncthreads();
  int x = v;
  for (int off=1; off<1024; off<<=1){
    int y = (t >= off) ? sh[t-off] : 0;
    __syncthreads();
    x += y; sh[t] = x;
    __syncthreads();
  }
  if (i < N) rowptr[i] = x - v;
  if (t == 1023) bsum[blockIdx.x] = x;
}

__global__ __launch_bounds__(64) void k_scan2(int* __restrict__ bsum, int nb){
  int l = threadIdx.x;
  int v0 = (l < nb) ? bsum[l] : 0;
  int v = v0;
  for (int off=1; off<64; off<<=1){
    int y = __shfl_up(v, off);
    if (l >= off) v += y;
  }
  if (l < nb) bsum[l] = v - v0;
}

__global__ __launch_bounds__(1024) void k_scan3(int* __restrict__ rowptr, const int* __restrict__ bsum,
                                                int N, int E){
  int i = blockIdx.x*1024 + threadIdx.x;
  if (i < N) rowptr[i] += bsum[blockIdx.x];
  if (i == 0) rowptr[N] = E;
}

// scatter edge PAYLOADS (src id + ef value) into CSR order — no eidx indirection later
__global__ __launch_bounds__(256) void k_scatter(const int* __restrict__ dst, const int* __restrict__ src,
                                                 const float* __restrict__ ef,
                                                 const int* __restrict__ rowptr,
                                                 int* __restrict__ fill,
                                                 int* __restrict__ ssrc, float* __restrict__ sef, int E){
  int i = blockIdx.x*256 + threadIdx.x;
  if (i < E){
    int d_ = dst[i];
    int pos = rowptr[d_] + atomicAdd(&fill[d_], 1);
    ssrc[pos] = src[i];
    sef[pos]  = ef[i];
  }
}

// ---------------- K5: per-dst-node: p=exp(e) + sum + g + MLP -> fi
__global__ __launch_bounds__(256) void k_node(
    const float* __restrict__ Qb, const float* __restrict__ Kb, const float* __restrict__ Tb,
    const float* __restrict__ WeQ, const float* __restrict__ t_in,
    const int* __restrict__ rowptr, const int* __restrict__ ssrc, const float* __restrict__ sef,
    const float* __restrict__ Wi, const float* __restrict__ bi,
    const float* __restrict__ wiw, const float* __restrict__ scale_i,
    float* __restrict__ es, float* __restrict__ esum,
    float* __restrict__ fi_out, int N)
{
  __shared__ float sWi[128*17];
  __shared__ float sbi[128];
  __shared__ float swiw[128];
  __shared__ float sscale[8];
  __shared__ float g_sh[4][4][17];
  int tid = threadIdx.x;
  for (int i=tid; i<128*17; i+=256) sWi[i] = Wi[i];
  if (tid < 128){ sbi[tid] = bi[tid]; swiw[tid] = wiw[tid]; }
  if (tid < 8)  sscale[tid] = __expf(scale_i[tid]);
  __syncthreads();

  int w = tid>>6, l = tid&63;
  int h = l>>4, il = l&15;
  int n = blockIdx.x*4 + w;
  bool act = (n < N);

  if (act){
    int row0 = rowptr[n];
    int dg   = rowptr[n+1] - row0;
    float q_l = Qb[(size_t)n*64 + l] * 0.25f;      // fold 1/sqrt(d)
    float weq = WeQ[n*4 + h] * 0.25f;
    float s_h = 0.f, g_l = 0.f;

    for (int c0=0; c0<dg; c0+=64){
      int cnt = min(dg - c0, 64);
      int   sn_v = 0; float ef_v = 0.f;
      if (l < cnt){ sn_v = ssrc[row0+c0+l]; ef_v = sef[row0+c0+l]; }
      size_t base = (size_t)(row0 + c0);
      int i2 = 0;
      for (; i2+4 <= cnt; i2+=4){
        int   sn0=__shfl(sn_v,i2+0), sn1=__shfl(sn_v,i2+1), sn2=__shfl(sn_v,i2+2), sn3=__shfl(sn_v,i2+3);
        float e0=__shfl(ef_v,i2+0),  e1=__shfl(ef_v,i2+1),  e2=__shfl(ef_v,i2+2),  e3=__shfl(ef_v,i2+3);
        float kv0=Kb[(size_t)sn0*64+l], kv1=Kb[(size_t)sn1*64+l], kv2=Kb[(size_t)sn2*64+l], kv3=Kb[(size_t)sn3*64+l];
        float tv0=Tb[(size_t)sn0*64+l], tv1=Tb[(size_t)sn1*64+l], tv2=Tb[(size_t)sn2*64+l], tv3=Tb[(size_t)sn3*64+l];
        float r0=red16(kv0*q_l), r1=red16(kv1*q_l), r2=red16(kv2*q_l), r3=red16(kv3*q_l);
        float p0=__expf(fmaf(e0,weq,r0)), p1=__expf(fmaf(e1,weq,r1));
        float p2=__expf(fmaf(e2,weq,r2)), p3=__expf(fmaf(e3,weq,r3));
        s_h += (p0+p1)+(p2+p3);
        g_l = fmaf(tv0,p0,g_l); g_l = fmaf(tv1,p1,g_l);
        g_l = fmaf(tv2,p2,g_l); g_l = fmaf(tv3,p3,g_l);
        if (il == h){
          es[(base+i2+0)*4+h]=p0; es[(base+i2+1)*4+h]=p1;
          es[(base+i2+2)*4+h]=p2; es[(base+i2+3)*4+h]=p3;
        }
      }
      for (; i2 < cnt; i2++){
        int   sn = __shfl(sn_v,i2);
        float ev = __shfl(ef_v,i2);
        float kv = Kb[(size_t)sn*64+l];
        float tv = Tb[(size_t)sn*64+l];
        float p  = __expf(fmaf(ev,weq,red16(kv*q_l)));
        s_h += p; g_l = fmaf(tv,p,g_l);
        if (il == h) es[(base+i2)*4+h] = p;
      }
    }

    if (il == h) esum[n*4+h] = s_h;
    float invs = (dg > 0) ? 1.f/s_h : 0.f;
    g_l *= invs;
    g_sh[w][h][il] = g_l;
    if (l < 4) g_sh[w][l][16] = t_in[n];
  }
  __syncthreads();
  if (act){
    float wi1[17], wi2[17];
    #pragma unroll
    for (int j=0;j<17;j++){ wi1[j] = sWi[l*17 + j]; wi2[j] = sWi[(l+64)*17 + j]; }
    float b1 = sbi[l],  b2 = sbi[l+64];
    float wv1 = swiw[l], wv2 = swiw[l+64];
    float z1[4], z2[4];
    #pragma unroll
    for (int h2=0; h2<4; h2++){
      float a1=b1, a2=b2;
      #pragma unroll
      for (int j=0;j<17;j++){
        float inj = g_sh[w][h2][j];
        a1 = fmaf(wi1[j], inj, a1);
        a2 = fmaf(wi2[j], inj, a2);
      }
      float u1 = __fdividef(1.f, 1.f + __expf(-a1));
      float u2 = __fdividef(1.f, 1.f + __expf(-a2));
      float p1 = u1*wv1, p2 = u2*wv2;
      p1 += __shfl_xor(p1,1); p1 += __shfl_xor(p1,2); p1 += __shfl_xor(p1,4); p1 += __shfl_xor(p1,8);
      p2 += __shfl_xor(p2,1); p2 += __shfl_xor(p2,2); p2 += __shfl_xor(p2,4); p2 += __shfl_xor(p2,8);
      z1[h2] = p1; z2[h2] = p2;
    }
    if (il == 0){
      int m1 = h;
      float sc1 = sscale[m1], sc2 = sscale[m1+4];
      #pragma unroll
      for (int h2=0; h2<4; h2++){
        fi_out[(size_t)n*32 + h2*8 + m1    ] = sc1*softplus_f(z1[h2]/sc1);
        fi_out[(size_t)n*32 + h2*8 + m1 + 4] = sc2*softplus_f(z2[h2]/sc2);
      }
    }
  }
}

// ---------------- K6: out[n] = x_dst[n] + (1/s) * sum_e V[src]*( (fi[src]·fm[n]) * p_e )
__global__ __launch_bounds__(256) void k_out(
    const float* __restrict__ Vb, const float* __restrict__ fi,
    const float* __restrict__ es, const float* __restrict__ esum,
    const float* __restrict__ m_in, const float* __restrict__ x_dst,
    const int* __restrict__ rowptr, const int* __restrict__ ssrc,
    float* __restrict__ out, int N)
{
  int tid = threadIdx.x;
  int w = tid>>6, l = tid&63;
  int h = l>>4;
  int n = blockIdx.x*4 + w;
  if (n >= N) return;
  const float4* fi4 = (const float4*)fi;
  float4 fm0 = *(const float4*)(m_in + (size_t)n*8);
  float4 fm1 = *(const float4*)(m_in + (size_t)n*8 + 4);
  float sh = esum[n*4+h];
  int row0 = rowptr[n], dg = rowptr[n+1] - row0;
  float invs = (dg > 0 && sh > 0.f) ? 1.f/sh : 0.f;
  float oacc = 0.f;

  for (int c0=0; c0<dg; c0+=64){
    int cnt = min(dg - c0, 64);
    int sn_v = 0;
    if (l < cnt) sn_v = ssrc[row0+c0+l];
    size_t base = (size_t)(row0 + c0);
    int i2 = 0;
    for (; i2+4 <= cnt; i2+=4){
      int sn0=__shfl(sn_v,i2+0), sn1=__shfl(sn_v,i2+1), sn2=__shfl(sn_v,i2+2), sn3=__shfl(sn_v,i2+3);
      float pe0=es[(base+i2+0)*4+h], pe1=es[(base+i2+1)*4+h];
      float pe2=es[(base+i2+2)*4+h], pe3=es[(base+i2+3)*4+h];
      float4 a0=fi4[(size_t)sn0*8+2*h], b0=fi4[(size_t)sn0*8+2*h+1];
      float4 a1=fi4[(size_t)sn1*8+2*h], b1=fi4[(size_t)sn1*8+2*h+1];
      float4 a2=fi4[(size_t)sn2*8+2*h], b2=fi4[(size_t)sn2*8+2*h+1];
      float4 a3=fi4[(size_t)sn3*8+2*h], b3=fi4[(size_t)sn3*8+2*h+1];
      float vv0=Vb[(size_t)sn0*64+l], vv1=Vb[(size_t)sn1*64+l];
      float vv2=Vb[(size_t)sn2*64+l], vv3=Vb[(size_t)sn3*64+l];
      float d0 = fmaf(a0.x,fm0.x, fmaf(a0.y,fm0.y, fmaf(a0.z,fm0.z, fmaf(a0.w,fm0.w,
                 fmaf(b0.x,fm1.x, fmaf(b0.y,fm1.y, fmaf(b0.z,fm1.z, b0.w*fm1.w)))))));
      float d1 = fmaf(a1.x,fm0.x, fmaf(a1.y,fm0.y, fmaf(a1.z,fm0.z, fmaf(a1.w,fm0.w,
                 fmaf(b1.x,fm1.x, fmaf(b1.y,fm1.y, fmaf(b1.z,fm1.z, b1.w*fm1.w)))))));
      float d2 = fmaf(a2.x,fm0.x, fmaf(a2.y,fm0.y, fmaf(a2.z,fm0.z, fmaf(a2.w,fm0.w,
                 fmaf(b2.x,fm1.x, fmaf(b2.y,fm1.y, fmaf(b2.z,fm1.z, b2.w*fm1.w)))))));
      float d3 = fmaf(a3.x,fm0.x, fmaf(a3.y,fm0.y, fmaf(a3.z,fm0.z, fmaf(a3.w,fm0.w,
                 fmaf(b3.x,fm1.x, fmaf(b3.y,fm1.y, fmaf(b3.z,fm1.z, b3.w*fm1.w)))))));
      oacc = fmaf(vv0, d0*pe0, oacc);
      oacc = fmaf(vv1, d1*pe1, oacc);
      oacc = fmaf(vv2, d2*pe2, oacc);
      oacc = fmaf(vv3, d3*pe3, oacc);
    }
    for (; i2 < cnt; i2++){
      int sn = __shfl(sn_v,i2);
      float pe = es[(base+i2)*4+h];
      float4 a = fi4[(size_t)sn*8+2*h], b = fi4[(size_t)sn*8+2*h+1];
      float vv = Vb[(size_t)sn*64+l];
      float dt = fmaf(a.x,fm0.x, fmaf(a.y,fm0.y, fmaf(a.z,fm0.z, fmaf(a.w,fm0.w,
                 fmaf(b.x,fm1.x, fmaf(b.y,fm1.y, fmaf(b.z,fm1.z, b.w*fm1.w)))))));
      oacc = fmaf(vv, dt*pe, oacc);
    }
  }
  out[(size_t)n*64 + l] = fmaf(oacc, invs, x_dst[(size_t)n*64 + l]);
}

extern "C" void kernel_launch(void* const* d_in, const int* in_sizes, int n_in,
                              void* d_out, int out_size, void* d_ws, size_t ws_size,
                              hipStream_t stream)
{
  const float* x_src = (const float*)d_in[0];
  const float* x_dst = (const float*)d_in[1];
  const float* t_in  = (const float*)d_in[2];
  const float* m_in  = (const float*)d_in[3];
  const float* ef    = (const float*)d_in[4];
  const float* Wq    = (const float*)d_in[5];
  const float* Wk    = (const float*)d_in[6];
  const float* Wv    = (const float*)d_in[7];
  const float* Wt    = (const float*)d_in[8];
  const float* We    = (const float*)d_in[9];
  const float* Wi    = (const float*)d_in[10];
  const float* bi    = (const float*)d_in[11];
  const float* wiw   = (const float*)d_in[12];
  const float* sci   = (const float*)d_in[13];
  const int*   src   = (const int*)d_in[14];
  const int*   dst   = (const int*)d_in[15];
  int N = in_sizes[0] / 64;
  int E = in_sizes[14];
  float* out = (float*)d_out;

  char* p = (char*)d_ws;
  auto alloc = [&](size_t bytes)->char*{ char* r = p; p += (bytes + 255) & ~(size_t)255; return r; };
  float* Qb   = (float*)alloc((size_t)N*64*4);
  float* Kb   = (float*)alloc((size_t)N*64*4);
  float* Tb   = (float*)alloc((size_t)N*64*4);
  float* Vb   = (float*)alloc((size_t)N*64*4);
  float* WeQ  = (float*)alloc((size_t)N*4*4);
  float* esum = (float*)alloc((size_t)N*4*4);
  float* fi   = (float*)alloc((size_t)N*32*4);
  float* es   = (float*)alloc((size_t)E*4*4);
  int*   deg  = (int*)alloc((size_t)N*4);
  int*   fill = (int*)alloc((size_t)N*4);
  int*   rowp = (int*)alloc((size_t)(N+1)*4);
  int*   ssrc = (int*)alloc((size_t)E*4);
  float* sef  = (float*)alloc((size_t)E*4);
  int    NB   = (N + 1023) / 1024;
  int*   bsum = (int*)alloc((size_t)NB*4);

  hipMemsetAsync(deg,  0, (size_t)N*4, stream);
  hipMemsetAsync(fill, 0, (size_t)N*4, stream);

  k_proj<<<(N+63)/64, 256, 0, stream>>>(x_src, x_dst, Wq, Wk, Wt, Wv, We, Qb, Kb, Tb, Vb, WeQ, N);
  k_hist<<<(E+255)/256, 256, 0, stream>>>(dst, deg, E);
  k_scan1<<<NB, 1024, 0, stream>>>(deg, rowp, bsum, N);
  k_scan2<<<1, 64, 0, stream>>>(bsum, NB);
  k_scan3<<<NB, 1024, 0, stream>>>(rowp, bsum, N, E);
  k_scatter<<<(E+255)/256, 256, 0, stream>>>(dst, src, ef, rowp, fill, ssrc, sef, E);
  k_node<<<(N+3)/4, 256, 0, stream>>>(Qb, Kb, Tb, WeQ, t_in, rowp, ssrc, sef,
                                      Wi, bi, wiw, sci, es, esum, fi, N);
  k_out<<<(N+3)/4, 256, 0, stream>>>(Vb, fi, es, esum, m_in, x_dst, rowp, ssrc, out, N);
}

// Round 6
// 433.156 us; speedup vs baseline: 1.4827x; 1.0901x over previous
//
#include <hip/hip_runtime.h>
#include <cmath>

// N=50000, E=800000, B=1, F=D=64, H=4, d=16, M=8.
// Wave (64 lanes) == one node's (h,dd): lane l -> h=l>>4, dd=l&15.
// K/T/V/fi stored bf16 to shrink the randomly-gathered working set (L2 thrash fix).

__device__ __forceinline__ float softplus_f(float z){
  return fmaxf(z, 0.f) + log1pf(__expf(-fabsf(z)));
}

__device__ __forceinline__ float red16(float v){
  v += __shfl_xor(v,1); v += __shfl_xor(v,2);
  v += __shfl_xor(v,4); v += __shfl_xor(v,8);
  return v;
}

__device__ __forceinline__ unsigned short f2bf(float x){   // RNE bf16
  unsigned int u = __float_as_uint(x);
  unsigned int r = (u + 0x7fffu + ((u>>16)&1u)) >> 16;
  return (unsigned short)r;
}
__device__ __forceinline__ unsigned int pack2bf(float a, float b){
  return (unsigned int)f2bf(a) | ((unsigned int)f2bf(b) << 16);
}
__device__ __forceinline__ float bflo(unsigned int u){ return __uint_as_float(u << 16); }
__device__ __forceinline__ float bfhi(unsigned int u){ return __uint_as_float(u & 0xffff0000u); }

// ---------------- K1: projections. mat0: Q f32 + WeQ; mat1: K bf16; mat2: T bf16; mat3: V bf16
__global__ __launch_bounds__(256) void k_proj(
    const float* __restrict__ x_src, const float* __restrict__ x_dst,
    const float* __restrict__ Wq, const float* __restrict__ Wk,
    const float* __restrict__ Wt, const float* __restrict__ Wv,
    const float* __restrict__ We,
    float* __restrict__ Qo, unsigned short* __restrict__ K16,
    unsigned short* __restrict__ T16, unsigned short* __restrict__ V16,
    float* __restrict__ WeQ, int N)
{
  int l   = threadIdx.x & 63;
  int mat = threadIdx.x >> 6;
  int n   = blockIdx.x * 64 + l;
  if (n >= N) return;
  const float* x = ((mat==0) ? x_dst : x_src) + (size_t)n*64;
  const float* W = (mat==0) ? Wq : (mat==1) ? Wk : (mat==2) ? Wt : Wv;
  unsigned short* O16 = (mat==1) ? K16 : (mat==2) ? T16 : V16;

  float xr[64];
  const float4* x4 = (const float4*)x;
  #pragma unroll
  for (int i=0;i<16;i++){ float4 v=x4[i]; xr[4*i]=v.x; xr[4*i+1]=v.y; xr[4*i+2]=v.z; xr[4*i+3]=v.w; }

  float4* Q4 = (float4*)(Qo + (size_t)n*64);
  float weq0=0.f, weq1=0.f, weq2=0.f, weq3=0.f;
  #pragma unroll
  for (int jq=0;jq<16;jq++){
    float a0=0.f,a1=0.f,a2=0.f,a3=0.f;
    const float* Wr = W + jq*256;
    #pragma unroll
    for (int f=0;f<64;f++){
      float xf = xr[f];
      a0 = fmaf(Wr[      f], xf, a0);
      a1 = fmaf(Wr[ 64 + f], xf, a1);
      a2 = fmaf(Wr[128 + f], xf, a2);
      a3 = fmaf(Wr[192 + f], xf, a3);
    }
    if (mat==0){
      Q4[jq] = make_float4(a0,a1,a2,a3);
      float ws = We[jq*4]*a0 + We[jq*4+1]*a1 + We[jq*4+2]*a2 + We[jq*4+3]*a3;
      if      (jq <  4) weq0 += ws;
      else if (jq <  8) weq1 += ws;
      else if (jq < 12) weq2 += ws;
      else              weq3 += ws;
    } else {
      *(uint2*)(O16 + (size_t)n*64 + jq*4) = make_uint2(pack2bf(a0,a1), pack2bf(a2,a3));
    }
  }
  if (mat==0) *(float4*)(WeQ + (size_t)n*4) = make_float4(weq0,weq1,weq2,weq3);
}

// ---------------- CSR build
__global__ __launch_bounds__(256) void k_hist(const int* __restrict__ dst, int* __restrict__ deg, int E){
  int i = blockIdx.x*256 + threadIdx.x;
  if (i < E) atomicAdd(&deg[dst[i]], 1);
}

__global__ __launch_bounds__(1024) void k_scan1(const int* __restrict__ deg, int* __restrict__ rowptr,
                                                int* __restrict__ bsum, int N){
  __shared__ int sh[1024];
  int t = threadIdx.x;
  int i = blockIdx.x*1024 + t;
  int v = (i < N) ? deg[i] : 0;
  sh[t] = v; __syncthreads();
  int x = v;
  for (int off=1; off<1024; off<<=1){
    int y = (t >= off) ? sh[t-off] : 0;
    __syncthreads();
    x += y; sh[t] = x;
    __syncthreads();
  }
  if (i < N) rowptr[i] = x - v;
  if (t == 1023) bsum[blockIdx.x] = x;
}

__global__ __launch_bounds__(64) void k_scan2(int* __restrict__ bsum, int nb){
  int l = threadIdx.x;
  int v0 = (l < nb) ? bsum[l] : 0;
  int v = v0;
  for (int off=1; off<64; off<<=1){
    int y = __shfl_up(v, off);
    if (l >= off) v += y;
  }
  if (l < nb) bsum[l] = v - v0;
}

__global__ __launch_bounds__(1024) void k_scan3(int* __restrict__ rowptr, const int* __restrict__ bsum,
                                                int N, int E){
  int i = blockIdx.x*1024 + threadIdx.x;
  if (i < N) rowptr[i] += bsum[blockIdx.x];
  if (i == 0) rowptr[N] = E;
}

// scatter packed edge payload {src, ef_bits} into CSR order
__global__ __launch_bounds__(256) void k_scatter(const int* __restrict__ dst, const int* __restrict__ src,
                                                 const float* __restrict__ ef,
                                                 const int* __restrict__ rowptr,
                                                 int* __restrict__ fill,
                                                 int2* __restrict__ sedge, int E){
  int i = blockIdx.x*256 + threadIdx.x;
  if (i < E){
    int d_ = dst[i];
    int pos = rowptr[d_] + atomicAdd(&fill[d_], 1);
    sedge[pos] = make_int2(src[i], __float_as_int(ef[i]));
  }
}

// ---------------- K5: per-dst-node: p=exp(e) + sum + g + MLP -> fi (bf16)
__global__ __launch_bounds__(256) void k_node(
    const float* __restrict__ Qb, const unsigned short* __restrict__ K16,
    const unsigned short* __restrict__ T16,
    const float* __restrict__ WeQ, const float* __restrict__ t_in,
    const int* __restrict__ rowptr, const int2* __restrict__ sedge,
    const float* __restrict__ Wi, const float* __restrict__ bi,
    const float* __restrict__ wiw, const float* __restrict__ scale_i,
    float* __restrict__ es, float* __restrict__ esum,
    unsigned short* __restrict__ fi16, int N)
{
  __shared__ float sWi[128*17];
  __shared__ float sbi[128];
  __shared__ float swiw[128];
  __shared__ float sscale[8];
  __shared__ float g_sh[4][4][17];
  int tid = threadIdx.x;
  for (int i=tid; i<128*17; i+=256) sWi[i] = Wi[i];
  if (tid < 128){ sbi[tid] = bi[tid]; swiw[tid] = wiw[tid]; }
  if (tid < 8)  sscale[tid] = __expf(scale_i[tid]);
  __syncthreads();

  int w = tid>>6, l = tid&63;
  int h = l>>4, il = l&15;
  int n = blockIdx.x*4 + w;
  bool act = (n < N);

  if (act){
    int row0 = rowptr[n];
    int dg   = rowptr[n+1] - row0;
    float q_l = Qb[(size_t)n*64 + l] * 0.25f;      // fold 1/sqrt(d)
    float weq = WeQ[n*4 + h] * 0.25f;
    float s_h = 0.f, g_l = 0.f;

    for (int c0=0; c0<dg; c0+=64){
      int cnt = min(dg - c0, 64);
      int sn_v = 0; float ef_v = 0.f;
      if (l < cnt){ int2 pv = sedge[row0+c0+l]; sn_v = pv.x; ef_v = __int_as_float(pv.y); }
      size_t base = (size_t)(row0 + c0);
      int i2 = 0;
      for (; i2+4 <= cnt; i2+=4){
        int   sn0=__shfl(sn_v,i2+0), sn1=__shfl(sn_v,i2+1), sn2=__shfl(sn_v,i2+2), sn3=__shfl(sn_v,i2+3);
        float e0=__shfl(ef_v,i2+0),  e1=__shfl(ef_v,i2+1),  e2=__shfl(ef_v,i2+2),  e3=__shfl(ef_v,i2+3);
        float kv0=bflo((unsigned)K16[(size_t)sn0*64+l]<<16 >> 16), kv1, kv2, kv3;
        // (expression above would be wrong; do plain loads below)
        kv0 = __uint_as_float((unsigned)K16[(size_t)sn0*64+l] << 16);
        kv1 = __uint_as_float((unsigned)K16[(size_t)sn1*64+l] << 16);
        kv2 = __uint_as_float((unsigned)K16[(size_t)sn2*64+l] << 16);
        kv3 = __uint_as_float((unsigned)K16[(size_t)sn3*64+l] << 16);
        float tv0 = __uint_as_float((unsigned)T16[(size_t)sn0*64+l] << 16);
        float tv1 = __uint_as_float((unsigned)T16[(size_t)sn1*64+l] << 16);
        float tv2 = __uint_as_float((unsigned)T16[(size_t)sn2*64+l] << 16);
        float tv3 = __uint_as_float((unsigned)T16[(size_t)sn3*64+l] << 16);
        float r0=red16(kv0*q_l), r1=red16(kv1*q_l), r2=red16(kv2*q_l), r3=red16(kv3*q_l);
        float p0=__expf(fmaf(e0,weq,r0)), p1=__expf(fmaf(e1,weq,r1));
        float p2=__expf(fmaf(e2,weq,r2)), p3=__expf(fmaf(e3,weq,r3));
        s_h += (p0+p1)+(p2+p3);
        g_l = fmaf(tv0,p0,g_l); g_l = fmaf(tv1,p1,g_l);
        g_l = fmaf(tv2,p2,g_l); g_l = fmaf(tv3,p3,g_l);
        if (il == h){
          es[(base+i2+0)*4+h]=p0; es[(base+i2+1)*4+h]=p1;
          es[(base+i2+2)*4+h]=p2; es[(base+i2+3)*4+h]=p3;
        }
      }
      for (; i2 < cnt; i2++){
        int   sn = __shfl(sn_v,i2);
        float ev = __shfl(ef_v,i2);
        float kv = __uint_as_float((unsigned)K16[(size_t)sn*64+l] << 16);
        float tv = __uint_as_float((unsigned)T16[(size_t)sn*64+l] << 16);
        float p  = __expf(fmaf(ev,weq,red16(kv*q_l)));
        s_h += p; g_l = fmaf(tv,p,g_l);
        if (il == h) es[(base+i2)*4+h] = p;
      }
    }

    if (il == h) esum[n*4+h] = s_h;
    float invs = (dg > 0) ? 1.f/s_h : 0.f;
    g_l *= invs;
    g_sh[w][h][il] = g_l;
    if (l < 4) g_sh[w][l][16] = t_in[n];
  }
  __syncthreads();
  if (act){
    float wi1[17], wi2[17];
    #pragma unroll
    for (int j=0;j<17;j++){ wi1[j] = sWi[l*17 + j]; wi2[j] = sWi[(l+64)*17 + j]; }
    float b1 = sbi[l],  b2 = sbi[l+64];
    float wv1 = swiw[l], wv2 = swiw[l+64];
    float z1[4], z2[4];
    #pragma unroll
    for (int h2=0; h2<4; h2++){
      float a1=b1, a2=b2;
      #pragma unroll
      for (int j=0;j<17;j++){
        float inj = g_sh[w][h2][j];
        a1 = fmaf(wi1[j], inj, a1);
        a2 = fmaf(wi2[j], inj, a2);
      }
      float u1 = __fdividef(1.f, 1.f + __expf(-a1));
      float u2 = __fdividef(1.f, 1.f + __expf(-a2));
      float p1 = u1*wv1, p2 = u2*wv2;
      p1 += __shfl_xor(p1,1); p1 += __shfl_xor(p1,2); p1 += __shfl_xor(p1,4); p1 += __shfl_xor(p1,8);
      p2 += __shfl_xor(p2,1); p2 += __shfl_xor(p2,2); p2 += __shfl_xor(p2,4); p2 += __shfl_xor(p2,8);
      z1[h2] = p1; z2[h2] = p2;
    }
    if (il == 0){
      int m1 = h;
      float sc1 = sscale[m1], sc2 = sscale[m1+4];
      #pragma unroll
      for (int h2=0; h2<4; h2++){
        fi16[(size_t)n*32 + h2*8 + m1    ] = f2bf(sc1*softplus_f(z1[h2]/sc1));
        fi16[(size_t)n*32 + h2*8 + m1 + 4] = f2bf(sc2*softplus_f(z2[h2]/sc2));
      }
    }
  }
}

// ---------------- K6: out[n] = x_dst[n] + (1/s) * sum_e V[src]*( (fi[src]·fm[n]) * p_e )
__global__ __launch_bounds__(256) void k_out(
    const unsigned short* __restrict__ V16, const unsigned short* __restrict__ fi16,
    const float* __restrict__ es, const float* __restrict__ esum,
    const float* __restrict__ m_in, const float* __restrict__ x_dst,
    const int* __restrict__ rowptr, const int2* __restrict__ sedge,
    float* __restrict__ out, int N)
{
  int tid = threadIdx.x;
  int w = tid>>6, l = tid&63;
  int h = l>>4;
  int n = blockIdx.x*4 + w;
  if (n >= N) return;
  float fm[8];
  #pragma unroll
  for (int mm=0; mm<8; mm++) fm[mm] = m_in[(size_t)n*8 + mm];
  float sh = esum[n*4+h];
  int row0 = rowptr[n], dg = rowptr[n+1] - row0;
  float invs = (dg > 0 && sh > 0.f) ? 1.f/sh : 0.f;
  float oacc = 0.f;

  for (int c0=0; c0<dg; c0+=64){
    int cnt = min(dg - c0, 64);
    int sn_v = 0;
    if (l < cnt) sn_v = sedge[row0+c0+l].x;
    size_t base = (size_t)(row0 + c0);
    int i2 = 0;
    for (; i2+4 <= cnt; i2+=4){
      int sn0=__shfl(sn_v,i2+0), sn1=__shfl(sn_v,i2+1), sn2=__shfl(sn_v,i2+2), sn3=__shfl(sn_v,i2+3);
      float pe0=es[(base+i2+0)*4+h], pe1=es[(base+i2+1)*4+h];
      float pe2=es[(base+i2+2)*4+h], pe3=es[(base+i2+3)*4+h];
      uint4 f0 = *(const uint4*)(fi16 + (size_t)sn0*32 + h*8);
      uint4 f1 = *(const uint4*)(fi16 + (size_t)sn1*32 + h*8);
      uint4 f2 = *(const uint4*)(fi16 + (size_t)sn2*32 + h*8);
      uint4 f3 = *(const uint4*)(fi16 + (size_t)sn3*32 + h*8);
      float vv0 = __uint_as_float((unsigned)V16[(size_t)sn0*64+l] << 16);
      float vv1 = __uint_as_float((unsigned)V16[(size_t)sn1*64+l] << 16);
      float vv2 = __uint_as_float((unsigned)V16[(size_t)sn2*64+l] << 16);
      float vv3 = __uint_as_float((unsigned)V16[(size_t)sn3*64+l] << 16);
      float d0 = fmaf(bflo(f0.x),fm[0], fmaf(bfhi(f0.x),fm[1], fmaf(bflo(f0.y),fm[2], fmaf(bfhi(f0.y),fm[3],
                 fmaf(bflo(f0.z),fm[4], fmaf(bfhi(f0.z),fm[5], fmaf(bflo(f0.w),fm[6], bfhi(f0.w)*fm[7])))))));
      float d1 = fmaf(bflo(f1.x),fm[0], fmaf(bfhi(f1.x),fm[1], fmaf(bflo(f1.y),fm[2], fmaf(bfhi(f1.y),fm[3],
                 fmaf(bflo(f1.z),fm[4], fmaf(bfhi(f1.z),fm[5], fmaf(bflo(f1.w),fm[6], bfhi(f1.w)*fm[7])))))));
      float d2 = fmaf(bflo(f2.x),fm[0], fmaf(bfhi(f2.x),fm[1], fmaf(bflo(f2.y),fm[2], fmaf(bfhi(f2.y),fm[3],
                 fmaf(bflo(f2.z),fm[4], fmaf(bfhi(f2.z),fm[5], fmaf(bflo(f2.w),fm[6], bfhi(f2.w)*fm[7])))))));
      float d3 = fmaf(bflo(f3.x),fm[0], fmaf(bfhi(f3.x),fm[1], fmaf(bflo(f3.y),fm[2], fmaf(bfhi(f3.y),fm[3],
                 fmaf(bflo(f3.z),fm[4], fmaf(bfhi(f3.z),fm[5], fmaf(bflo(f3.w),fm[6], bfhi(f3.w)*fm[7])))))));
      oacc = fmaf(vv0, d0*pe0, oacc);
      oacc = fmaf(vv1, d1*pe1, oacc);
      oacc = fmaf(vv2, d2*pe2, oacc);
      oacc = fmaf(vv3, d3*pe3, oacc);
    }
    for (; i2 < cnt; i2++){
      int sn = __shfl(sn_v,i2);
      float pe = es[(base+i2)*4+h];
      uint4 f0 = *(const uint4*)(fi16 + (size_t)sn*32 + h*8);
      float vv = __uint_as_float((unsigned)V16[(size_t)sn*64+l] << 16);
      float dt = fmaf(bflo(f0.x),fm[0], fmaf(bfhi(f0.x),fm[1], fmaf(bflo(f0.y),fm[2], fmaf(bfhi(f0.y),fm[3],
                 fmaf(bflo(f0.z),fm[4], fmaf(bfhi(f0.z),fm[5], fmaf(bflo(f0.w),fm[6], bfhi(f0.w)*fm[7])))))));
      oacc = fmaf(vv, dt*pe, oacc);
    }
  }
  out[(size_t)n*64 + l] = fmaf(oacc, invs, x_dst[(size_t)n*64 + l]);
}

extern "C" void kernel_launch(void* const* d_in, const int* in_sizes, int n_in,
                              void* d_out, int out_size, void* d_ws, size_t ws_size,
                              hipStream_t stream)
{
  const float* x_src = (const float*)d_in[0];
  const float* x_dst = (const float*)d_in[1];
  const float* t_in  = (const float*)d_in[2];
  const float* m_in  = (const float*)d_in[3];
  const float* ef    = (const float*)d_in[4];
  const float* Wq    = (const float*)d_in[5];
  const float* Wk    = (const float*)d_in[6];
  const float* Wv    = (const float*)d_in[7];
  const float* Wt    = (const float*)d_in[8];
  const float* We    = (const float*)d_in[9];
  const float* Wi    = (const float*)d_in[10];
  const float* bi    = (const float*)d_in[11];
  const float* wiw   = (const float*)d_in[12];
  const float* sci   = (const float*)d_in[13];
  const int*   src   = (const int*)d_in[14];
  const int*   dst   = (const int*)d_in[15];
  int N = in_sizes[0] / 64;
  int E = in_sizes[14];
  float* out = (float*)d_out;

  char* p = (char*)d_ws;
  auto alloc = [&](size_t bytes)->char*{ char* r = p; p += (bytes + 255) & ~(size_t)255; return r; };
  float*          Qb   = (float*)alloc((size_t)N*64*4);
  unsigned short* K16  = (unsigned short*)alloc((size_t)N*64*2);
  unsigned short* T16  = (unsigned short*)alloc((size_t)N*64*2);
  unsigned short* V16  = (unsigned short*)alloc((size_t)N*64*2);
  float*          WeQ  = (float*)alloc((size_t)N*4*4);
  float*          esum = (float*)alloc((size_t)N*4*4);
  unsigned short* fi16 = (unsigned short*)alloc((size_t)N*32*2);
  float*          es   = (float*)alloc((size_t)E*4*4);
  int*            deg  = (int*)alloc((size_t)N*4);
  int*            fill = (int*)alloc((size_t)N*4);
  int*            rowp = (int*)alloc((size_t)(N+1)*4);
  int2*           sedge= (int2*)alloc((size_t)E*8);
  int             NB   = (N + 1023) / 1024;
  int*            bsum = (int*)alloc((size_t)NB*4);

  hipMemsetAsync(deg,  0, (size_t)N*4, stream);
  hipMemsetAsync(fill, 0, (size_t)N*4, stream);

  k_proj<<<(N+63)/64, 256, 0, stream>>>(x_src, x_dst, Wq, Wk, Wt, Wv, We, Qb, K16, T16, V16, WeQ, N);
  k_hist<<<(E+255)/256, 256, 0, stream>>>(dst, deg, E);
  k_scan1<<<NB, 1024, 0, stream>>>(deg, rowp, bsum, N);
  k_scan2<<<1, 64, 0, stream>>>(bsum, NB);
  k_scan3<<<NB, 1024, 0, stream>>>(rowp, bsum, N, E);
  k_scatter<<<(E+255)/256, 256, 0, stream>>>(dst, src, ef, rowp, fill, sedge, E);
  k_node<<<(N+3)/4, 256, 0, stream>>>(Qb, K16, T16, WeQ, t_in, rowp, sedge,
                                      Wi, bi, wiw, sci, es, esum, fi16, N);
  k_out<<<(N+3)/4, 256, 0, stream>>>(V16, fi16, es, esum, m_in, x_dst, rowp, sedge, out, N);
}